// Round 4
// baseline (79.700 us; speedup 1.0000x reference)
//
#include <hip/hip_runtime.h>
#include <math.h>

// Segment mean via counting-sort by node bucket, then LDS reduce.
// bucket = dst >> 8 (391 buckets x 256 nodes), NC=2048 chunks for occupancy.
// pairs entry: (f32 value rounded to 24 bits) | (8-bit intra-bucket node idx)

#define PACK_MAGIC 4294967296.0   // 2^32
#define NB 391                    // ceil(100000 / 256)
#define BSHIFT 8
#define SNODES 256
#define NC 2048                   // chunks (= blocks) for hist/scatter

__device__ __forceinline__ unsigned pack_pair(float v, int local) {
    unsigned b = __float_as_uint(v);
    b = (b + 0x80u) & 0xFFFFFF00u;           // round mantissa to 15 bits
    return b | (unsigned)local;
}

// ---------- sort-based path ----------

__global__ void hist_kernel(const int* __restrict__ dst, int* __restrict__ hist,
                            int n_edges, int chunk) {
    __shared__ int h[NB];
    for (int i = threadIdx.x; i < NB; i += blockDim.x) h[i] = 0;
    __syncthreads();
    int beg = blockIdx.x * chunk;
    int end = min(beg + chunk, n_edges);
    for (int i = beg + threadIdx.x; i < end; i += blockDim.x)
        atomicAdd(&h[dst[i] >> BSHIFT], 1);
    __syncthreads();
    for (int b = threadIdx.x; b < NB; b += blockDim.x)
        hist[(size_t)blockIdx.x * NB + b] = h[b];
}

// one block (64 threads) per bucket: exclusive scan down the chunk column
__global__ void scan_col_kernel(int* __restrict__ hist, int* __restrict__ totals) {
    int b = blockIdx.x;
    int lane = threadIdx.x;  // 64
    int carry = 0;
    for (int c0 = 0; c0 < NC; c0 += 64) {
        int v = hist[(size_t)(c0 + lane) * NB + b];
        int s = v;
        for (int off = 1; off < 64; off <<= 1) {
            int t = __shfl_up(s, off);
            if (lane >= off) s += t;
        }
        hist[(size_t)(c0 + lane) * NB + b] = carry + (s - v);  // exclusive
        carry += __shfl(s, 63);
    }
    if (lane == 0) totals[b] = carry;
}

// one wave: exclusive scan over NB bucket totals -> base[NB+1]
__global__ void scan_base_kernel(const int* __restrict__ totals, int* __restrict__ base) {
    int lane = threadIdx.x;  // 64
    const int K = (NB + 63) / 64;  // 7
    int vals[7];
    int local = 0;
    for (int k = 0; k < K; ++k) {
        int idx = lane * K + k;
        int v = (idx < NB) ? totals[idx] : 0;
        vals[k] = v; local += v;
    }
    int s = local;
    for (int off = 1; off < 64; off <<= 1) {
        int t = __shfl_up(s, off);
        if (lane >= off) s += t;
    }
    int ex = s - local;
    int total = __shfl(s, 63);
    for (int k = 0; k < K; ++k) {
        int idx = lane * K + k;
        if (idx < NB) base[idx] = ex;
        ex += vals[k];
    }
    if (lane == 0) base[NB] = total;
}

__global__ void scatter_sort_kernel(const float* __restrict__ edge_x,
                                    const int* __restrict__ dst,
                                    const int* __restrict__ hist,
                                    const int* __restrict__ base,
                                    unsigned* __restrict__ pairs,
                                    int n_edges, int chunk) {
    __shared__ int cur[NB];
    for (int b = threadIdx.x; b < NB; b += blockDim.x)
        cur[b] = base[b] + hist[(size_t)blockIdx.x * NB + b];
    __syncthreads();
    int beg = blockIdx.x * chunk;
    int end = min(beg + chunk, n_edges);
    for (int i = beg + threadIdx.x; i < end; i += blockDim.x) {
        int d = dst[i];
        float v = edge_x[(size_t)i * 8];
        int pos = atomicAdd(&cur[d >> BSHIFT], 1);   // LDS atomic
        pairs[pos] = pack_pair(v, d & (SNODES - 1));
    }
}

__global__ void reduce_kernel(const unsigned* __restrict__ pairs,
                              const int* __restrict__ base,
                              float* __restrict__ out, int n_nodes) {
    __shared__ double acc[SNODES];
    int b = blockIdx.x;
    for (int i = threadIdx.x; i < SNODES; i += blockDim.x) acc[i] = 0.0;
    __syncthreads();
    int beg = base[b], end = base[b + 1];
    for (int i = beg + threadIdx.x; i < end; i += blockDim.x) {
        unsigned p = pairs[i];
        float v = __uint_as_float(p & 0xFFFFFF00u);
        atomicAdd(&acc[p & 0xFFu], (double)v + PACK_MAGIC);
    }
    __syncthreads();
    int node0 = b << BSHIFT;
    for (int i = threadIdx.x; i < SNODES; i += blockDim.x) {
        int node = node0 + i;
        if (node < n_nodes) {
            double x = acc[i];
            double c = nearbyint(x * (1.0 / PACK_MAGIC));
            double s = x - c * PACK_MAGIC;
            out[node] = (c > 0.0) ? (float)(s / c) : 0.0f;
        }
    }
}

// ---------- fallback: packed-f64 atomic path ----------

__global__ void zero_ws_kernel(double* __restrict__ ws, int n) {
    int i = blockIdx.x * blockDim.x + threadIdx.x;
    int stride = gridDim.x * blockDim.x;
    for (; i < n; i += stride) ws[i] = 0.0;
}

__global__ void scatter_atomic_kernel(const float* __restrict__ edge_x,
                                      const int* __restrict__ dst,
                                      double* __restrict__ part,
                                      int n_edges, int n_nodes, int r_mask) {
    int t = blockIdx.x * blockDim.x + threadIdx.x;
    int base = t * 4;
    double* my = part + (size_t)(blockIdx.x & r_mask) * (size_t)n_nodes;
    if (base + 3 < n_edges) {
        int4 d4 = *reinterpret_cast<const int4*>(dst + base);
        float v0 = edge_x[(size_t)(base + 0) * 8];
        float v1 = edge_x[(size_t)(base + 1) * 8];
        float v2 = edge_x[(size_t)(base + 2) * 8];
        float v3 = edge_x[(size_t)(base + 3) * 8];
        atomicAdd(&my[d4.x], (double)v0 + PACK_MAGIC);
        atomicAdd(&my[d4.y], (double)v1 + PACK_MAGIC);
        atomicAdd(&my[d4.z], (double)v2 + PACK_MAGIC);
        atomicAdd(&my[d4.w], (double)v3 + PACK_MAGIC);
    } else {
        for (int i = base; i < n_edges; ++i) {
            float v = edge_x[(size_t)i * 8];
            atomicAdd(&my[dst[i]], (double)v + PACK_MAGIC);
        }
    }
}

__global__ void finalize_atomic_kernel(const double* __restrict__ part,
                                       float* __restrict__ out, int n_nodes, int R) {
    int i = blockIdx.x * blockDim.x + threadIdx.x;
    if (i >= n_nodes) return;
    double x = 0.0;
    for (int r = 0; r < R; ++r) x += part[(size_t)r * n_nodes + i];
    double c = nearbyint(x * (1.0 / PACK_MAGIC));
    double s = x - c * PACK_MAGIC;
    out[i] = (c > 0.0) ? (float)(s / c) : 0.0f;
}

// ---------- launch ----------

extern "C" void kernel_launch(void* const* d_in, const int* in_sizes, int n_in,
                              void* d_out, int out_size, void* d_ws, size_t ws_size,
                              hipStream_t stream) {
    const float* edge_x = (const float*)d_in[0];
    const int*   dst    = (const int*)d_in[1];
    float* out = (float*)d_out;

    const int n_nodes = out_size;        // 100000
    const int n_edges = in_sizes[1];     // 3200000

    size_t pairs_bytes = (size_t)n_edges * sizeof(unsigned);
    size_t hist_bytes  = (size_t)NC * NB * sizeof(int);
    size_t base_bytes  = (size_t)(NB + 1) * sizeof(int);
    size_t tot_bytes   = (size_t)NB * sizeof(int);
    size_t need = pairs_bytes + hist_bytes + base_bytes + tot_bytes;

    if (ws_size >= need && n_nodes <= NB * SNODES) {
        unsigned* pairs  = (unsigned*)d_ws;
        int*  hist   = (int*)((char*)d_ws + pairs_bytes);
        int*  basep  = (int*)((char*)hist + hist_bytes);
        int*  totals = (int*)((char*)basep + base_bytes);

        int chunk = (n_edges + NC - 1) / NC;

        hist_kernel<<<NC, 256, 0, stream>>>(dst, hist, n_edges, chunk);
        scan_col_kernel<<<NB, 64, 0, stream>>>(hist, totals);
        scan_base_kernel<<<1, 64, 0, stream>>>(totals, basep);
        scatter_sort_kernel<<<NC, 256, 0, stream>>>(edge_x, dst, hist, basep,
                                                    pairs, n_edges, chunk);
        reduce_kernel<<<NB, 512, 0, stream>>>(pairs, basep, out, n_nodes);
    } else {
        int R = 1;
        while (R < 8 && (size_t)(R * 2) * (size_t)n_nodes * sizeof(double) <= ws_size) R *= 2;
        double* part = (double*)d_ws;
        {
            int n = R * n_nodes;
            int blocks = min((n + 255) / 256, 2048);
            zero_ws_kernel<<<blocks, 256, 0, stream>>>(part, n);
        }
        {
            int nthreads = (n_edges + 3) / 4;
            int blocks = (nthreads + 255) / 256;
            scatter_atomic_kernel<<<blocks, 256, 0, stream>>>(edge_x, dst, part,
                                                              n_edges, n_nodes, R - 1);
        }
        {
            int blocks = (n_nodes + 255) / 256;
            finalize_atomic_kernel<<<blocks, 256, 0, stream>>>(part, out, n_nodes, R);
        }
    }
}

// Round 5
// 63.491 us; speedup vs baseline: 1.2553x; 1.2553x over previous
//
#include <hip/hip_runtime.h>
#include <math.h>

// Segment mean via two-level counting sort:
//   pass1: per-chunk histogram over 391 node-buckets (dst>>8)
//   pass2: column scan (chunk offsets -> choff), bucket totals
//   pass3: bucket base scan
//   pass4: block-local LDS counting sort of the chunk, then per-bucket
//          run-coalesced writeout of packed (val24|local8) entries
//   pass5: per-bucket LDS packed-double reduce -> mean
// Fallback to packed-f64-atomic scatter if ws is too small.

#define PACK_MAGIC 4294967296.0   // 2^32
#define NB 391                    // ceil(100000 / 256)
#define BSHIFT 8
#define SNODES 256
#define NC 512                    // chunks (= blocks) for hist/scatter
#define CMAX 6400                 // max edges per chunk staged in LDS

__device__ __forceinline__ unsigned pack_pair(float v, int local) {
    unsigned b = __float_as_uint(v);
    b = (b + 0x80u) & 0xFFFFFF00u;           // round mantissa to 15 bits
    return b | (unsigned)local;
}

// ---------- sort-based path ----------

__global__ void hist_kernel(const int* __restrict__ dst, int* __restrict__ hist,
                            int n_edges, int chunk) {
    __shared__ int h[NB];
    for (int i = threadIdx.x; i < NB; i += blockDim.x) h[i] = 0;
    __syncthreads();
    int beg = blockIdx.x * chunk;
    int end = min(beg + chunk, n_edges);
    for (int i = beg + threadIdx.x; i < end; i += blockDim.x)
        atomicAdd(&h[dst[i] >> BSHIFT], 1);
    __syncthreads();
    for (int b = threadIdx.x; b < NB; b += blockDim.x)
        hist[(size_t)blockIdx.x * NB + b] = h[b];
}

// one block (64 threads) per bucket: exclusive scan down the chunk column.
// hist preserved; choff gets per-chunk exclusive offsets; totals[b] = bucket size.
__global__ void scan_col_kernel(const int* __restrict__ hist,
                                int* __restrict__ choff,
                                int* __restrict__ totals) {
    int b = blockIdx.x;
    int lane = threadIdx.x;  // 64
    int carry = 0;
    for (int c0 = 0; c0 < NC; c0 += 64) {
        int v = hist[(size_t)(c0 + lane) * NB + b];
        int s = v;
        for (int off = 1; off < 64; off <<= 1) {
            int t = __shfl_up(s, off);
            if (lane >= off) s += t;
        }
        choff[(size_t)(c0 + lane) * NB + b] = carry + (s - v);  // exclusive
        carry += __shfl(s, 63);
    }
    if (lane == 0) totals[b] = carry;
}

// one wave: exclusive scan over NB bucket totals -> base[NB+1]
__global__ void scan_base_kernel(const int* __restrict__ totals, int* __restrict__ base) {
    int lane = threadIdx.x;  // 64
    const int K = (NB + 63) / 64;  // 7
    int vals[7];
    int local = 0;
    for (int k = 0; k < K; ++k) {
        int idx = lane * K + k;
        int v = (idx < NB) ? totals[idx] : 0;
        vals[k] = v; local += v;
    }
    int s = local;
    for (int off = 1; off < 64; off <<= 1) {
        int t = __shfl_up(s, off);
        if (lane >= off) s += t;
    }
    int ex = s - local;
    int total = __shfl(s, 63);
    for (int k = 0; k < K; ++k) {
        int idx = lane * K + k;
        if (idx < NB) base[idx] = ex;
        ex += vals[k];
    }
    if (lane == 0) base[NB] = total;
}

// block-local counting sort of the chunk in LDS, then run-coalesced writeout
__global__ void scatter_sort_kernel(const float* __restrict__ edge_x,
                                    const int* __restrict__ dst,
                                    const int* __restrict__ hist,
                                    const int* __restrict__ choff,
                                    const int* __restrict__ base,
                                    unsigned* __restrict__ pairs,
                                    int n_edges, int chunk) {
    __shared__ unsigned s_pack[CMAX];
    __shared__ int h[NB];      // this chunk's bucket counts (= run lengths)
    __shared__ int startp[NB]; // local exclusive starts
    __shared__ int cnt[NB];    // local cursors
    __shared__ int gbase[NB];  // global write base per bucket

    int tid = threadIdx.x;
    int blk = blockIdx.x;

    for (int b = tid; b < NB; b += blockDim.x) {
        h[b] = hist[(size_t)blk * NB + b];
        gbase[b] = base[b] + choff[(size_t)blk * NB + b];
    }
    __syncthreads();

    // wave 0: exclusive scan of h -> startp, cnt
    if (tid < 64) {
        int lane = tid;
        const int K = (NB + 63) / 64;  // 7
        int vals[7];
        int local = 0;
        for (int k = 0; k < K; ++k) {
            int idx = lane * K + k;
            int v = (idx < NB) ? h[idx] : 0;
            vals[k] = v; local += v;
        }
        int s = local;
        for (int off = 1; off < 64; off <<= 1) {
            int t = __shfl_up(s, off);
            if (lane >= off) s += t;
        }
        int ex = s - local;
        for (int k = 0; k < K; ++k) {
            int idx = lane * K + k;
            if (idx < NB) { startp[idx] = ex; cnt[idx] = ex; }
            ex += vals[k];
        }
    }
    __syncthreads();

    // stage: sort chunk entries into LDS by bucket
    int beg = blk * chunk;
    int end = min(beg + chunk, n_edges);
    for (int i = beg + tid; i < end; i += blockDim.x) {
        int d = dst[i];
        float v = edge_x[(size_t)i * 8];
        int pos = atomicAdd(&cnt[d >> BSHIFT], 1);   // LDS atomic
        s_pack[pos] = pack_pair(v, d & (SNODES - 1));
    }
    __syncthreads();

    // writeout: one wave per bucket run, contiguous stores
    int wave = tid >> 6, lane = tid & 63;
    int nwaves = blockDim.x >> 6;
    for (int b = wave; b < NB; b += nwaves) {
        int len = h[b];
        int sp = startp[b];
        int gp = gbase[b];
        for (int j = lane; j < len; j += 64)
            pairs[gp + j] = s_pack[sp + j];
    }
}

__global__ void reduce_kernel(const unsigned* __restrict__ pairs,
                              const int* __restrict__ base,
                              float* __restrict__ out, int n_nodes) {
    __shared__ double acc[SNODES];
    int b = blockIdx.x;
    for (int i = threadIdx.x; i < SNODES; i += blockDim.x) acc[i] = 0.0;
    __syncthreads();
    int beg = base[b], end = base[b + 1];
    for (int i = beg + threadIdx.x; i < end; i += blockDim.x) {
        unsigned p = pairs[i];
        float v = __uint_as_float(p & 0xFFFFFF00u);
        atomicAdd(&acc[p & 0xFFu], (double)v + PACK_MAGIC);
    }
    __syncthreads();
    int node0 = b << BSHIFT;
    for (int i = threadIdx.x; i < SNODES; i += blockDim.x) {
        int node = node0 + i;
        if (node < n_nodes) {
            double x = acc[i];
            double c = nearbyint(x * (1.0 / PACK_MAGIC));
            double s = x - c * PACK_MAGIC;
            out[node] = (c > 0.0) ? (float)(s / c) : 0.0f;
        }
    }
}

// ---------- fallback: packed-f64 atomic path ----------

__global__ void zero_ws_kernel(double* __restrict__ ws, int n) {
    int i = blockIdx.x * blockDim.x + threadIdx.x;
    int stride = gridDim.x * blockDim.x;
    for (; i < n; i += stride) ws[i] = 0.0;
}

__global__ void scatter_atomic_kernel(const float* __restrict__ edge_x,
                                      const int* __restrict__ dst,
                                      double* __restrict__ part,
                                      int n_edges, int n_nodes, int r_mask) {
    int t = blockIdx.x * blockDim.x + threadIdx.x;
    int basei = t * 4;
    double* my = part + (size_t)(blockIdx.x & r_mask) * (size_t)n_nodes;
    if (basei + 3 < n_edges) {
        int4 d4 = *reinterpret_cast<const int4*>(dst + basei);
        float v0 = edge_x[(size_t)(basei + 0) * 8];
        float v1 = edge_x[(size_t)(basei + 1) * 8];
        float v2 = edge_x[(size_t)(basei + 2) * 8];
        float v3 = edge_x[(size_t)(basei + 3) * 8];
        atomicAdd(&my[d4.x], (double)v0 + PACK_MAGIC);
        atomicAdd(&my[d4.y], (double)v1 + PACK_MAGIC);
        atomicAdd(&my[d4.z], (double)v2 + PACK_MAGIC);
        atomicAdd(&my[d4.w], (double)v3 + PACK_MAGIC);
    } else {
        for (int i = basei; i < n_edges; ++i) {
            float v = edge_x[(size_t)i * 8];
            atomicAdd(&my[dst[i]], (double)v + PACK_MAGIC);
        }
    }
}

__global__ void finalize_atomic_kernel(const double* __restrict__ part,
                                       float* __restrict__ out, int n_nodes, int R) {
    int i = blockIdx.x * blockDim.x + threadIdx.x;
    if (i >= n_nodes) return;
    double x = 0.0;
    for (int r = 0; r < R; ++r) x += part[(size_t)r * n_nodes + i];
    double c = nearbyint(x * (1.0 / PACK_MAGIC));
    double s = x - c * PACK_MAGIC;
    out[i] = (c > 0.0) ? (float)(s / c) : 0.0f;
}

// ---------- launch ----------

extern "C" void kernel_launch(void* const* d_in, const int* in_sizes, int n_in,
                              void* d_out, int out_size, void* d_ws, size_t ws_size,
                              hipStream_t stream) {
    const float* edge_x = (const float*)d_in[0];
    const int*   dst    = (const int*)d_in[1];
    float* out = (float*)d_out;

    const int n_nodes = out_size;        // 100000
    const int n_edges = in_sizes[1];     // 3200000

    size_t pairs_bytes = (size_t)n_edges * sizeof(unsigned);
    size_t hist_bytes  = (size_t)NC * NB * sizeof(int);
    size_t choff_bytes = hist_bytes;
    size_t base_bytes  = (size_t)(NB + 1) * sizeof(int);
    size_t tot_bytes   = (size_t)NB * sizeof(int);
    size_t need = pairs_bytes + hist_bytes + choff_bytes + base_bytes + tot_bytes;

    int chunk = (n_edges + NC - 1) / NC;

    if (ws_size >= need && n_nodes <= NB * SNODES && chunk <= CMAX) {
        unsigned* pairs  = (unsigned*)d_ws;
        int*  hist   = (int*)((char*)d_ws + pairs_bytes);
        int*  choff  = (int*)((char*)hist + hist_bytes);
        int*  basep  = (int*)((char*)choff + choff_bytes);
        int*  totals = (int*)((char*)basep + base_bytes);

        hist_kernel<<<NC, 256, 0, stream>>>(dst, hist, n_edges, chunk);
        scan_col_kernel<<<NB, 64, 0, stream>>>(hist, choff, totals);
        scan_base_kernel<<<1, 64, 0, stream>>>(totals, basep);
        scatter_sort_kernel<<<NC, 256, 0, stream>>>(edge_x, dst, hist, choff,
                                                    basep, pairs, n_edges, chunk);
        reduce_kernel<<<NB, 512, 0, stream>>>(pairs, basep, out, n_nodes);
    } else {
        int R = 1;
        while (R < 8 && (size_t)(R * 2) * (size_t)n_nodes * sizeof(double) <= ws_size) R *= 2;
        double* part = (double*)d_ws;
        {
            int n = R * n_nodes;
            int blocks = min((n + 255) / 256, 2048);
            zero_ws_kernel<<<blocks, 256, 0, stream>>>(part, n);
        }
        {
            int nthreads = (n_edges + 3) / 4;
            int blocks = (nthreads + 255) / 256;
            scatter_atomic_kernel<<<blocks, 256, 0, stream>>>(edge_x, dst, part,
                                                              n_edges, n_nodes, R - 1);
        }
        {
            int blocks = (n_nodes + 255) / 256;
            finalize_atomic_kernel<<<blocks, 256, 0, stream>>>(part, out, n_nodes, R);
        }
    }
}

// Round 6
// 51.272 us; speedup vs baseline: 1.5545x; 1.2383x over previous
//
#include <hip/hip_runtime.h>
#include <math.h>

// Segment mean via two-level counting sort.
//   pass1: per-chunk histogram over 391 node-buckets (dst>>8)
//   pass2: column scan -> per-chunk offsets (choff), bucket totals
//   pass3: bucket base scan
//   pass4: block-local LDS sort storing (global_dest | packed_val) u64;
//          writeout = flat parallel loop, run-contiguous global stores
//   pass5: per-bucket LDS packed-double reduce -> mean
// Fallback to packed-f64-atomic scatter if ws is too small.

#define PACK_MAGIC 4294967296.0   // 2^32
#define NB 391                    // ceil(100000 / 256)
#define BSHIFT 8
#define SNODES 256
#define NC 512                    // chunks (= blocks) for hist/scatter
#define CMAX 6400                 // max edges per chunk staged in LDS
#define STHREADS 512              // scatter block size

__device__ __forceinline__ unsigned pack_pair(float v, int local) {
    unsigned b = __float_as_uint(v);
    b = (b + 0x80u) & 0xFFFFFF00u;           // round mantissa to 15 bits
    return b | (unsigned)local;
}

// ---------- sort-based path ----------

__global__ void hist_kernel(const int* __restrict__ dst, int* __restrict__ hist,
                            int n_edges, int chunk) {
    __shared__ int h[NB];
    for (int i = threadIdx.x; i < NB; i += blockDim.x) h[i] = 0;
    __syncthreads();
    int beg = blockIdx.x * chunk;
    int end = min(beg + chunk, n_edges);
    for (int i = beg + threadIdx.x; i < end; i += blockDim.x)
        atomicAdd(&h[dst[i] >> BSHIFT], 1);
    __syncthreads();
    for (int b = threadIdx.x; b < NB; b += blockDim.x)
        hist[(size_t)blockIdx.x * NB + b] = h[b];
}

// one block (64 threads) per bucket: exclusive scan down the chunk column.
__global__ void scan_col_kernel(const int* __restrict__ hist,
                                int* __restrict__ choff,
                                int* __restrict__ totals) {
    int b = blockIdx.x;
    int lane = threadIdx.x;  // 64
    int carry = 0;
    for (int c0 = 0; c0 < NC; c0 += 64) {
        int v = hist[(size_t)(c0 + lane) * NB + b];
        int s = v;
        for (int off = 1; off < 64; off <<= 1) {
            int t = __shfl_up(s, off);
            if (lane >= off) s += t;
        }
        choff[(size_t)(c0 + lane) * NB + b] = carry + (s - v);  // exclusive
        carry += __shfl(s, 63);
    }
    if (lane == 0) totals[b] = carry;
}

// one wave: exclusive scan over NB bucket totals -> base[NB+1]
__global__ void scan_base_kernel(const int* __restrict__ totals, int* __restrict__ base) {
    int lane = threadIdx.x;  // 64
    const int K = (NB + 63) / 64;  // 7
    int vals[7];
    int local = 0;
    for (int k = 0; k < K; ++k) {
        int idx = lane * K + k;
        int v = (idx < NB) ? totals[idx] : 0;
        vals[k] = v; local += v;
    }
    int s = local;
    for (int off = 1; off < 64; off <<= 1) {
        int t = __shfl_up(s, off);
        if (lane >= off) s += t;
    }
    int ex = s - local;
    int total = __shfl(s, 63);
    for (int k = 0; k < K; ++k) {
        int idx = lane * K + k;
        if (idx < NB) base[idx] = ex;
        ex += vals[k];
    }
    if (lane == 0) base[NB] = total;
}

// block-local counting sort into LDS u64 (dest<<32 | pack), flat writeout
__global__ void __launch_bounds__(STHREADS)
scatter_sort_kernel(const float* __restrict__ edge_x,
                    const int* __restrict__ dst,
                    const int* __restrict__ hist,
                    const int* __restrict__ choff,
                    const int* __restrict__ base,
                    unsigned* __restrict__ pairs,
                    int n_edges, int chunk) {
    __shared__ unsigned long long s_data[CMAX];
    __shared__ int h[NB];      // chunk bucket counts
    __shared__ int cnt[NB];    // local cursors (start at startp)
    __shared__ int delta[NB];  // gbase - startp  (dest = delta + pos)

    int tid = threadIdx.x;
    int blk = blockIdx.x;

    for (int b = tid; b < NB; b += blockDim.x) {
        h[b] = hist[(size_t)blk * NB + b];
        delta[b] = base[b] + choff[(size_t)blk * NB + b];  // gbase for now
    }
    __syncthreads();

    // wave 0: exclusive scan of h -> cnt (=startp); delta -= startp
    if (tid < 64) {
        int lane = tid;
        const int K = (NB + 63) / 64;  // 7
        int vals[7];
        int local = 0;
        for (int k = 0; k < K; ++k) {
            int idx = lane * K + k;
            int v = (idx < NB) ? h[idx] : 0;
            vals[k] = v; local += v;
        }
        int s = local;
        for (int off = 1; off < 64; off <<= 1) {
            int t = __shfl_up(s, off);
            if (lane >= off) s += t;
        }
        int ex = s - local;
        for (int k = 0; k < K; ++k) {
            int idx = lane * K + k;
            if (idx < NB) { cnt[idx] = ex; delta[idx] -= ex; }
            ex += vals[k];
        }
    }
    __syncthreads();

    int beg = blk * chunk;
    int end = min(beg + chunk, n_edges);
    int chunkN = end - beg;

    // staging: strip-mined x4 — batch loads, then commit
    {
        int i = beg + tid;
        int step = blockDim.x;
        for (; i + 3 * step < end; i += 4 * step) {
            int d0 = dst[i];
            int d1 = dst[i + step];
            int d2 = dst[i + 2 * step];
            int d3 = dst[i + 3 * step];
            float v0 = edge_x[(size_t)i * 8];
            float v1 = edge_x[(size_t)(i + step) * 8];
            float v2 = edge_x[(size_t)(i + 2 * step) * 8];
            float v3 = edge_x[(size_t)(i + 3 * step) * 8];
            int p0 = atomicAdd(&cnt[d0 >> BSHIFT], 1);
            s_data[p0] = ((unsigned long long)(unsigned)(delta[d0 >> BSHIFT] + p0) << 32)
                       | pack_pair(v0, d0 & (SNODES - 1));
            int p1 = atomicAdd(&cnt[d1 >> BSHIFT], 1);
            s_data[p1] = ((unsigned long long)(unsigned)(delta[d1 >> BSHIFT] + p1) << 32)
                       | pack_pair(v1, d1 & (SNODES - 1));
            int p2 = atomicAdd(&cnt[d2 >> BSHIFT], 1);
            s_data[p2] = ((unsigned long long)(unsigned)(delta[d2 >> BSHIFT] + p2) << 32)
                       | pack_pair(v2, d2 & (SNODES - 1));
            int p3 = atomicAdd(&cnt[d3 >> BSHIFT], 1);
            s_data[p3] = ((unsigned long long)(unsigned)(delta[d3 >> BSHIFT] + p3) << 32)
                       | pack_pair(v3, d3 & (SNODES - 1));
        }
        for (; i < end; i += step) {
            int d = dst[i];
            float v = edge_x[(size_t)i * 8];
            int p = atomicAdd(&cnt[d >> BSHIFT], 1);
            s_data[p] = ((unsigned long long)(unsigned)(delta[d >> BSHIFT] + p) << 32)
                      | pack_pair(v, d & (SNODES - 1));
        }
    }
    __syncthreads();

    // writeout: flat parallel, dest embedded; stores are run-contiguous
    for (int p = tid; p < chunkN; p += blockDim.x) {
        unsigned long long v = s_data[p];
        pairs[v >> 32] = (unsigned)v;
    }
}

__global__ void reduce_kernel(const unsigned* __restrict__ pairs,
                              const int* __restrict__ base,
                              float* __restrict__ out, int n_nodes) {
    __shared__ double acc[SNODES];
    int b = blockIdx.x;
    for (int i = threadIdx.x; i < SNODES; i += blockDim.x) acc[i] = 0.0;
    __syncthreads();
    int beg = base[b], end = base[b + 1];
    for (int i = beg + threadIdx.x; i < end; i += blockDim.x) {
        unsigned p = pairs[i];
        float v = __uint_as_float(p & 0xFFFFFF00u);
        atomicAdd(&acc[p & 0xFFu], (double)v + PACK_MAGIC);
    }
    __syncthreads();
    int node0 = b << BSHIFT;
    for (int i = threadIdx.x; i < SNODES; i += blockDim.x) {
        int node = node0 + i;
        if (node < n_nodes) {
            double x = acc[i];
            double c = nearbyint(x * (1.0 / PACK_MAGIC));
            double s = x - c * PACK_MAGIC;
            out[node] = (c > 0.0) ? (float)(s / c) : 0.0f;
        }
    }
}

// ---------- fallback: packed-f64 atomic path ----------

__global__ void zero_ws_kernel(double* __restrict__ ws, int n) {
    int i = blockIdx.x * blockDim.x + threadIdx.x;
    int stride = gridDim.x * blockDim.x;
    for (; i < n; i += stride) ws[i] = 0.0;
}

__global__ void scatter_atomic_kernel(const float* __restrict__ edge_x,
                                      const int* __restrict__ dst,
                                      double* __restrict__ part,
                                      int n_edges, int n_nodes, int r_mask) {
    int t = blockIdx.x * blockDim.x + threadIdx.x;
    int basei = t * 4;
    double* my = part + (size_t)(blockIdx.x & r_mask) * (size_t)n_nodes;
    if (basei + 3 < n_edges) {
        int4 d4 = *reinterpret_cast<const int4*>(dst + basei);
        float v0 = edge_x[(size_t)(basei + 0) * 8];
        float v1 = edge_x[(size_t)(basei + 1) * 8];
        float v2 = edge_x[(size_t)(basei + 2) * 8];
        float v3 = edge_x[(size_t)(basei + 3) * 8];
        atomicAdd(&my[d4.x], (double)v0 + PACK_MAGIC);
        atomicAdd(&my[d4.y], (double)v1 + PACK_MAGIC);
        atomicAdd(&my[d4.z], (double)v2 + PACK_MAGIC);
        atomicAdd(&my[d4.w], (double)v3 + PACK_MAGIC);
    } else {
        for (int i = basei; i < n_edges; ++i) {
            float v = edge_x[(size_t)i * 8];
            atomicAdd(&my[dst[i]], (double)v + PACK_MAGIC);
        }
    }
}

__global__ void finalize_atomic_kernel(const double* __restrict__ part,
                                       float* __restrict__ out, int n_nodes, int R) {
    int i = blockIdx.x * blockDim.x + threadIdx.x;
    if (i >= n_nodes) return;
    double x = 0.0;
    for (int r = 0; r < R; ++r) x += part[(size_t)r * n_nodes + i];
    double c = nearbyint(x * (1.0 / PACK_MAGIC));
    double s = x - c * PACK_MAGIC;
    out[i] = (c > 0.0) ? (float)(s / c) : 0.0f;
}

// ---------- launch ----------

extern "C" void kernel_launch(void* const* d_in, const int* in_sizes, int n_in,
                              void* d_out, int out_size, void* d_ws, size_t ws_size,
                              hipStream_t stream) {
    const float* edge_x = (const float*)d_in[0];
    const int*   dst    = (const int*)d_in[1];
    float* out = (float*)d_out;

    const int n_nodes = out_size;        // 100000
    const int n_edges = in_sizes[1];     // 3200000

    size_t pairs_bytes = (size_t)n_edges * sizeof(unsigned);
    size_t hist_bytes  = (size_t)NC * NB * sizeof(int);
    size_t choff_bytes = hist_bytes;
    size_t base_bytes  = (size_t)(NB + 1) * sizeof(int);
    size_t tot_bytes   = (size_t)NB * sizeof(int);
    size_t need = pairs_bytes + hist_bytes + choff_bytes + base_bytes + tot_bytes;

    int chunk = (n_edges + NC - 1) / NC;

    if (ws_size >= need && n_nodes <= NB * SNODES && chunk <= CMAX) {
        unsigned* pairs  = (unsigned*)d_ws;
        int*  hist   = (int*)((char*)d_ws + pairs_bytes);
        int*  choff  = (int*)((char*)hist + hist_bytes);
        int*  basep  = (int*)((char*)choff + choff_bytes);
        int*  totals = (int*)((char*)basep + base_bytes);

        hist_kernel<<<NC, 256, 0, stream>>>(dst, hist, n_edges, chunk);
        scan_col_kernel<<<NB, 64, 0, stream>>>(hist, choff, totals);
        scan_base_kernel<<<1, 64, 0, stream>>>(totals, basep);
        scatter_sort_kernel<<<NC, STHREADS, 0, stream>>>(edge_x, dst, hist, choff,
                                                         basep, pairs, n_edges, chunk);
        reduce_kernel<<<NB, 512, 0, stream>>>(pairs, basep, out, n_nodes);
    } else {
        int R = 1;
        while (R < 8 && (size_t)(R * 2) * (size_t)n_nodes * sizeof(double) <= ws_size) R *= 2;
        double* part = (double*)d_ws;
        {
            int n = R * n_nodes;
            int blocks = min((n + 255) / 256, 2048);
            zero_ws_kernel<<<blocks, 256, 0, stream>>>(part, n);
        }
        {
            int nthreads = (n_edges + 3) / 4;
            int blocks = (nthreads + 255) / 256;
            scatter_atomic_kernel<<<blocks, 256, 0, stream>>>(edge_x, dst, part,
                                                              n_edges, n_nodes, R - 1);
        }
        {
            int blocks = (n_nodes + 255) / 256;
            finalize_atomic_kernel<<<blocks, 256, 0, stream>>>(part, out, n_nodes, R);
        }
    }
}